// Round 2
// baseline (217.241 us; speedup 1.0000x reference)
//
#include <hip/hip_runtime.h>
#include <math.h>

// ---------------------------------------------------------------------------
// WaveletEmbedding: 4-level db4 2D DWT (symmetric) -> detail magnitudes ->
// bilinear upsample -> sigmoid gating.  B=16, C=2, H=W=512, N_SCALES=4.
// Level sizes: 512 -> 259 -> 133 -> 70 -> 38.  All I/O f32.
// Round 5b: even-padded row strides (260/134/70/38) so every level's rows are
// 8-B aligned -> interior taps load as 4x float2 (halves VMEM instrs, perfect
// coalescing); stage-2 computes output PAIRS (ds_read_b64 + float2 stores);
// edge-tile clipping (kmax/rmax); division-free patch staging; nontemporal
// final stores via clang ext_vector (HIP float4 is a class -> rejected by
// __builtin_nontemporal_store).
// ---------------------------------------------------------------------------

#define EPSV 1e-8f

typedef float f32x4 __attribute__((ext_vector_type(4)));

__constant__ float c_lo[8] = {
    -0.010597401784997278f,  0.032883011666982945f,  0.030841381835986965f,
    -0.18703481171888114f,  -0.02798376941698385f,   0.6308807679295904f,
     0.7148465705525415f,    0.23037781330885523f };
// DEC_HI[i] = DEC_LO[7-i] * (i even ? -1 : +1)
__constant__ float c_hi[8] = {
    -0.23037781330885523f,   0.7148465705525415f,   -0.6308807679295904f,
    -0.02798376941698385f,   0.18703481171888114f,   0.030841381835986965f,
    -0.032883011666982945f, -0.010597401784997278f };

__device__ __forceinline__ int symi(int i, int n) {
    i = (i < 0) ? (-1 - i) : i;
    i = (i >= n) ? (2 * n - 1 - i) : i;
    return i;
}

// ---------------- fused per-level DWT: in[N x N] -> cA,mag [M x M] ---------
// inStride/outStride are EVEN padded row strides (plane = rows * stride).
// AVG=true (level 4): mag <- 0.5*(LL + |detail|), no cA output.
template <int TO, bool AVG>
__global__ __launch_bounds__(256)
void dwt_level(const float* __restrict__ in, float* __restrict__ cA,
               float* __restrict__ mag, int N, int inStride,
               int M, int outStride, int tilesX) {
    static_assert(TO == 32, "TO must be 32");
    constexpr int R = 2 * TO + 6;                 // 70
    __shared__ float s_lo[R][TO + 2];             // stride 34 -> rows 8B-aligned
    __shared__ float s_hi[R][TO + 2];

    int T  = tilesX * tilesX;
    int n  = blockIdx.x / T;
    int t  = blockIdx.x % T;
    int tx = t % tilesX, ty = t / tilesX;
    int ox0 = tx * TO, oy0 = ty * TO;
    const float* img = in + (size_t)n * N * inStride;
    int qbase = 2 * oy0 - 6;
    int kmax = min(TO, M - ox0);                  // valid output cols this tile
    int rmax = 2 * min(TO, M - oy0) + 6;          // input rows actually needed

    // stage 1: row DWT for the rmax input rows needed by this tile
    for (int e = threadIdx.x; e < rmax * TO; e += 256) {
        int r = e >> 5, k = e & 31;
        if (k >= kmax) continue;
        int gq = symi(qbase + r, N);
        const float* row = img + (size_t)gq * inStride;
        int base = 2 * (ox0 + k) + 1;             // odd -> base-7 even -> 8B-aligned
        float lo, hi;
        if (base >= 7 && base < N) {              // all taps interior
            const float2* p2 = (const float2*)(row + (base - 7));
            float2 q0 = p2[0], q1 = p2[1], q2 = p2[2], q3 = p2[3];
            // tap(j) = row[base-j]: j=0..7 -> q3.y,q3.x,q2.y,q2.x,q1.y,q1.x,q0.y,q0.x
            lo = c_lo[0]*q3.y + c_lo[1]*q3.x + c_lo[2]*q2.y + c_lo[3]*q2.x
               + c_lo[4]*q1.y + c_lo[5]*q1.x + c_lo[6]*q0.y + c_lo[7]*q0.x;
            hi = c_hi[0]*q3.y + c_hi[1]*q3.x + c_hi[2]*q2.y + c_hi[3]*q2.x
               + c_hi[4]*q1.y + c_hi[5]*q1.x + c_hi[6]*q0.y + c_hi[7]*q0.x;
        } else {
            lo = 0.f; hi = 0.f;
#pragma unroll
            for (int j = 0; j < 8; ++j) {
                float x = row[symi(base - j, N)];
                lo += c_lo[j] * x;
                hi += c_hi[j] * x;
            }
        }
        s_lo[r][k] = lo;
        s_hi[r][k] = hi;
    }
    __syncthreads();

    // stage 2: column DWT from LDS -> output PAIRS (k, k+1) per thread
    for (int e = threadIdx.x; e < TO * TO / 2; e += 256) {
        int ly = e >> 4;                          // TO/2 = 16 pairs per row
        int k  = (e & 15) * 2;
        int oy = oy0 + ly, ox = ox0 + k;
        if (oy >= M || ox >= M) continue;
        float llx = 0.f, lly = 0.f, lhx = 0.f, lhy = 0.f;
        float hlx = 0.f, hly = 0.f, hhx = 0.f, hhy = 0.f;
#pragma unroll
        for (int j = 0; j < 8; ++j) {
            int r = 2 * ly + 7 - j;
            float2 a = *(const float2*)&s_lo[r][k];   // 8B-aligned (k even)
            float2 b = *(const float2*)&s_hi[r][k];
            llx += c_lo[j] * a.x;  lly += c_lo[j] * a.y;
            lhx += c_hi[j] * a.x;  lhy += c_hi[j] * a.y;
            hlx += c_lo[j] * b.x;  hly += c_lo[j] * b.y;
            hhx += c_hi[j] * b.x;  hhy += c_hi[j] * b.y;
        }
        size_t o = (size_t)n * M * outStride + (size_t)oy * outStride + ox;
        float mx = sqrtf(lhx * lhx + hlx * hlx + hhx * hhx + EPSV);
        float my = sqrtf(lhy * lhy + hly * hly + hhy * hhy + EPSV);
        bool pair = (ox + 1 < M);
        if (AVG) {
            float fx = 0.5f * (llx + mx);
            if (pair) {
                float fy = 0.5f * (lly + my);
                *(float2*)&mag[o] = make_float2(fx, fy);
            } else {
                mag[o] = fx;
            }
        } else {
            if (pair) {
                *(float2*)&cA[o]  = make_float2(llx, lly);
                *(float2*)&mag[o] = make_float2(mx, my);
            } else {
                cA[o]  = llx;
                mag[o] = mx;
            }
        }
    }
}

// ------------- final: gate + LDS-patch bilinear upsample + store -----------
// Block = 64x64 output tile of one (image n, scale s).  8 tiles/dim.
// Source patch (<=34x34 floats) staged in LDS; all bilerp taps hit LDS.
#define PMAX 34
#define PSTR 35
__global__ __launch_bounds__(256)
void final_kernel(const float* __restrict__ f0,   const float* __restrict__ mag3,
                  const float* __restrict__ mag2, const float* __restrict__ mag1,
                  const float* __restrict__ t_emb, const float* __restrict__ gate_w,
                  float* __restrict__ out) {
    __shared__ float patch[PMAX * PSTR];
    __shared__ float s_sw;

    int blk  = blockIdx.x;
    int tile = blk & 63;          // 8x8 tiles
    int s    = (blk >> 6) & 3;
    int n    = blk >> 8;          // image 0..31
    int b    = n >> 1, c = n & 1;
    int ti0  = (tile >> 3) * 64, tj0 = (tile & 7) * 64;

    const float* src; int ns, st;
    if      (s == 0) { src = f0;   ns = 38;  st = 38;  }
    else if (s == 1) { src = mag3; ns = 70;  st = 70;  }
    else if (s == 2) { src = mag2; ns = 133; st = 134; }
    else             { src = mag1; ns = 259; st = 260; }
    src += (size_t)n * ns * st;
    float sc = (float)ns * (1.0f / 512.0f);

    // gate weight (block-uniform): first wave reduces the 64-dot
    if (threadIdx.x < 64) {
        float v = t_emb[b * 64 + threadIdx.x] * gate_w[threadIdx.x * 4 + s];
#pragma unroll
        for (int off = 32; off > 0; off >>= 1) v += __shfl_down(v, off);
        if (threadIdx.x == 0) s_sw = 1.f / (1.f + expf(-v));
    }

    // source patch bounds covering output rows [ti0, ti0+63], cols [tj0, tj0+63]
    int pr0 = max(0, (int)floorf(((float)ti0 + 0.5f) * sc - 0.5f));
    int pr1 = min(ns - 1, (int)floorf(((float)ti0 + 63.5f) * sc - 0.5f) + 1);
    int pc0 = max(0, (int)floorf(((float)tj0 + 0.5f) * sc - 0.5f));
    int pc1 = min(ns - 1, (int)floorf(((float)tj0 + 63.5f) * sc - 0.5f) + 1);
    int rows = pr1 - pr0 + 1, cols = pc1 - pc0 + 1;

    // division-free 2D staging: 8 row-groups x 32-lane coalesced column sweeps
    for (int r = threadIdx.x >> 5; r < rows; r += 8) {
        const float* srow = src + (size_t)(pr0 + r) * st + pc0;
        float* prow = patch + r * PSTR;
        for (int cc = threadIdx.x & 31; cc < cols; cc += 32)
            prow[cc] = srow[cc];
    }
    __syncthreads();

    // thread -> 4 cols (tx*4..tx*4+3) x 4 rows (ty, ty+16, ty+32, ty+48)
    int tx = threadIdx.x & 15, ty = threadIdx.x >> 4;
    float sw = s_sw;

    // column weights, computed once, reused for all 4 rows
    int   j0r[4], j1r[4];
    float fjr[4];
#pragma unroll
    for (int q = 0; q < 4; ++q) {
        int j = tj0 + tx * 4 + q;
        float uj = ((float)j + 0.5f) * sc - 0.5f;
        float f0j = floorf(uj);
        int j0 = (int)f0j;
        fjr[q] = uj - f0j;
        j0r[q] = min(max(j0, 0), ns - 1) - pc0;
        j1r[q] = min(max(j0 + 1, 0), ns - 1) - pc0;
    }

    size_t obase = (((size_t)b * 8 + (c * 4 + s)) * 512) * 512;
#pragma unroll
    for (int rr = 0; rr < 4; ++rr) {
        int i = ti0 + ty + rr * 16;
        float ui = ((float)i + 0.5f) * sc - 0.5f;
        float f0i = floorf(ui);
        int i0 = (int)f0i;
        float fi = ui - f0i;
        const float* r0 = patch + (min(max(i0, 0), ns - 1) - pr0) * PSTR;
        const float* r1 = patch + (min(max(i0 + 1, 0), ns - 1) - pr0) * PSTR;
        f32x4 o;
#pragma unroll
        for (int q = 0; q < 4; ++q) {
            float v00 = r0[j0r[q]], v01 = r0[j1r[q]];
            float v10 = r1[j0r[q]], v11 = r1[j1r[q]];
            float t0 = v00 + (v01 - v00) * fjr[q];
            float t1 = v10 + (v11 - v10) * fjr[q];
            o[q] = (t0 + (t1 - t0) * fi) * sw;
        }
        // pure streaming output (never re-read): nontemporal to keep L2 for mags
        __builtin_nontemporal_store(o, (f32x4*)(out + obase + (size_t)i * 512 + tj0 + tx * 4));
    }
}

// ---------------------------------------------------------------------------
extern "C" void kernel_launch(void* const* d_in, const int* in_sizes, int n_in,
                              void* d_out, int out_size, void* d_ws, size_t ws_size,
                              hipStream_t stream) {
    (void)in_sizes; (void)n_in; (void)out_size; (void)ws_size;
    const float* image  = (const float*)d_in[0];
    const float* t_emb  = (const float*)d_in[1];
    const float* gate_w = (const float*)d_in[2];
    float* out = (float*)d_out;
    float* ws = (float*)d_ws;

    const int NI = 32;
    // padded plane sizes: rows * EVEN row stride
    const int P1 = 259 * 260, P2 = 133 * 134, P3 = 70 * 70, P4 = 38 * 38;

    size_t off = 0;
    float* mag1 = ws + off; off += (size_t)NI * P1;
    float* mag2 = ws + off; off += (size_t)NI * P2;
    float* mag3 = ws + off; off += (size_t)NI * P3;
    float* f0   = ws + off; off += (size_t)NI * P4;   // 0.5*(cA4+mag4)
    float* cA1  = ws + off; off += (size_t)NI * P1;
    float* cA2  = ws + off; off += (size_t)NI * P2;
    float* cA3  = ws + off; off += (size_t)NI * P3;

    const int TO = 32;
    auto tiles = [](int M) { return (M + TO - 1) / TO; };

    { int tX = tiles(259);   // 9
      dwt_level<TO, false><<<NI * tX * tX, 256, 0, stream>>>(image, cA1, mag1, 512, 512, 259, 260, tX); }
    { int tX = tiles(133);   // 5
      dwt_level<TO, false><<<NI * tX * tX, 256, 0, stream>>>(cA1, cA2, mag2, 259, 260, 133, 134, tX); }
    { int tX = tiles(70);    // 3
      dwt_level<TO, false><<<NI * tX * tX, 256, 0, stream>>>(cA2, cA3, mag3, 133, 134, 70, 70, tX); }
    { int tX = tiles(38);    // 2
      dwt_level<TO, true><<<NI * tX * tX, 256, 0, stream>>>(cA3, nullptr, f0, 70, 70, 38, 38, tX); }

    // final: 32 images x 4 scales x 64 tiles of 64x64
    final_kernel<<<32 * 4 * 64, 256, 0, stream>>>(f0, mag3, mag2, mag1,
                                                  t_emb, gate_w, out);
}